// Round 1
// baseline (8833.665 us; speedup 1.0000x reference)
//
#include <hip/hip_runtime.h>
#include <cstddef>

#define BDIM 32
#define LEN 32
#define DD 384
#define NCELLS 528

// off[k] = k*32 - k*(k-1)/2
__device__ __forceinline__ int offf(int k) { return k * 32 - ((k * (k - 1)) >> 1); }
static inline int offh(int k) { return k * 32 - ((k * (k - 1)) >> 1); }

__device__ __forceinline__ float sigma_h_f(float x) {
  float s = 1.0f / (1.0f + __expf(-x));      // sigmoid
  float r = sqrtf(s);
  float e2 = __expf(2.0f * r);
  float th = 1.0f - 2.0f / (e2 + 1.0f);      // tanh(r), r in (0,1)
  return x * th;
}

// ---------------------------------------------------------------------------
// pack: build Wcat[384][1920] = [in_W0 | in_W1 | in_bi | out_W1 | out_bi]
// and zero is_/os_ score arrays.
__global__ __launch_bounds__(256) void pack_k(
    const float* __restrict__ w0, const float* __restrict__ w1,
    const float* __restrict__ bi, const float* __restrict__ ow1,
    const float* __restrict__ obi, float* __restrict__ WC,
    float* __restrict__ isp, float* __restrict__ osp) {
  int i = blockIdx.x * 256 + threadIdx.x;
  if (i < 384 * 384) {
    int k = i / 384, c = i - k * 384;
    size_t rb = (size_t)k * 1920;
    WC[rb + c]        = w0[i];
    WC[rb + 384 + c]  = w1[i];
    WC[rb + 768 + c]  = bi[i];
    WC[rb + 1152 + c] = ow1[i];
    WC[rb + 1536 + c] = obi[i];
  }
  if (i < BDIM * NCELLS) { isp[i] = 0.0f; osp[i] = 0.0f; }
}

// ---------------------------------------------------------------------------
// Generic fp32 GEMM: C[M][N] = act(A[M][384] @ W[384][N] + bias)
// A rows: contiguous (gLs==0) or gathered per cell: b=r/gLs, cell=gOff+r%gLs,
// row ptr = A + (b*NCELLS+cell)*384. C rows use the same mapping with pitch N.
#define BM 64
#define BN 128
#define BK 32

__device__ __forceinline__ size_t rowbase(int r, int gLs, int gOff) {
  if (gLs == 0) return (size_t)r;
  int b = r / gLs;
  int p = r - b * gLs;
  return (size_t)b * NCELLS + gOff + p;
}

__global__ __launch_bounds__(256) void gemm_k(
    const float* __restrict__ A, const float* __restrict__ W,
    const float* __restrict__ bias, float* __restrict__ C,
    int M, int N, int act, int gLs, int gOff) {
  __shared__ float As[BK][BM + 4];   // k-major (transposed)
  __shared__ float Ws[BK][BN + 4];
  int tid = threadIdx.x;
  int m0 = blockIdx.x * BM;
  int n0 = blockIdx.y * BN;
  int rg = tid >> 4;   // 0..15 -> rows rg*4..+3
  int cg = tid & 15;   // 0..15 -> cols cg*8..+7

  float acc[4][8];
#pragma unroll
  for (int i = 0; i < 4; ++i)
#pragma unroll
    for (int j = 0; j < 8; ++j) acc[i][j] = 0.0f;

  int ar = tid >> 2;            // 0..63
  int ak = (tid & 3) << 3;      // 0,8,16,24
  int arow = m0 + ar;
  const float* Aptr = nullptr;
  if (arow < M) Aptr = A + rowbase(arow, gLs, gOff) * (size_t)DD;
  int wk = tid >> 3;            // 0..31
  int wn = (tid & 7) << 4;      // 0..112 step 16

  for (int k0 = 0; k0 < DD; k0 += BK) {
    float4 a0 = make_float4(0, 0, 0, 0), a1 = make_float4(0, 0, 0, 0);
    if (Aptr) {
      a0 = *reinterpret_cast<const float4*>(Aptr + k0 + ak);
      a1 = *reinterpret_cast<const float4*>(Aptr + k0 + ak + 4);
    }
    const float* wp = W + (size_t)(k0 + wk) * N + n0 + wn;
    float4 w0 = *reinterpret_cast<const float4*>(wp);
    float4 w1 = *reinterpret_cast<const float4*>(wp + 4);
    float4 w2 = *reinterpret_cast<const float4*>(wp + 8);
    float4 w3 = *reinterpret_cast<const float4*>(wp + 12);
    __syncthreads();
    As[ak + 0][ar] = a0.x; As[ak + 1][ar] = a0.y;
    As[ak + 2][ar] = a0.z; As[ak + 3][ar] = a0.w;
    As[ak + 4][ar] = a1.x; As[ak + 5][ar] = a1.y;
    As[ak + 6][ar] = a1.z; As[ak + 7][ar] = a1.w;
    *reinterpret_cast<float4*>(&Ws[wk][wn])      = w0;
    *reinterpret_cast<float4*>(&Ws[wk][wn + 4])  = w1;
    *reinterpret_cast<float4*>(&Ws[wk][wn + 8])  = w2;
    *reinterpret_cast<float4*>(&Ws[wk][wn + 12]) = w3;
    __syncthreads();
#pragma unroll
    for (int k = 0; k < BK; ++k) {
      float4 av  = *reinterpret_cast<const float4*>(&As[k][rg << 2]);
      float4 wv0 = *reinterpret_cast<const float4*>(&Ws[k][cg << 3]);
      float4 wv1 = *reinterpret_cast<const float4*>(&Ws[k][(cg << 3) + 4]);
      float a_[4] = {av.x, av.y, av.z, av.w};
      float w_[8] = {wv0.x, wv0.y, wv0.z, wv0.w, wv1.x, wv1.y, wv1.z, wv1.w};
#pragma unroll
      for (int i = 0; i < 4; ++i)
#pragma unroll
        for (int j = 0; j < 8; ++j) acc[i][j] += a_[i] * w_[j];
    }
  }
#pragma unroll
  for (int i = 0; i < 4; ++i) {
    int r = m0 + (rg << 2) + i;
    if (r >= M) continue;
    size_t cb = rowbase(r, gLs, gOff) * (size_t)N + n0 + (cg << 3);
#pragma unroll
    for (int j = 0; j < 8; ++j) {
      float v = acc[i][j];
      if (bias) v += bias[n0 + (cg << 3) + j];
      if (act) v = sigma_h_f(v);
      C[cb + j] = v;
    }
  }
}

// ---------------------------------------------------------------------------
// K1 inside: per (b,pos) group: scores sc[n], softmax p, sbar -> is_, and
// H rows = sigma_h(A0[l] + A1[r] + B0).
__global__ __launch_bounds__(256) void k1_in(
    const float* __restrict__ PC, const float* __restrict__ ihp,
    float* __restrict__ isp, float* __restrict__ H, float* __restrict__ Pw,
    const float* __restrict__ B0, int L, int Ls, int offL) {
  int g = blockIdx.x;
  int b = g / Ls, pos = g - b * Ls;
  int tid = threadIdx.x, lane = tid & 63, wv = tid >> 6;
  __shared__ float scs[32];
  size_t cb = (size_t)b * NCELLS;
  for (int n = wv; n < L; n += 4) {
    int lc = offf(n) + pos;
    int rc = offf(L - 1 - n) + pos + n + 1;
    const float* u = PC + (cb + lc) * 1920 + 768;   // Uin[l]
    const float* v = ihp + (cb + rc) * (size_t)DD;  // ih[r]
    float s = 0.0f;
#pragma unroll
    for (int jj = 0; jj < 6; ++jj) s += u[lane + 64 * jj] * v[lane + 64 * jj];
#pragma unroll
    for (int o = 32; o; o >>= 1) s += __shfl_xor(s, o, 64);
    if (lane == 0) scs[n] = s + isp[cb + lc] + isp[cb + rc];
  }
  __syncthreads();
  if (wv == 0) {
    float v = (lane < L) ? scs[lane] : -3.0e38f;
    float m = v;
#pragma unroll
    for (int o = 32; o; o >>= 1) m = fmaxf(m, __shfl_xor(m, o, 64));
    float e = (lane < L) ? __expf(v - m) : 0.0f;
    float S = e;
#pragma unroll
    for (int o = 32; o; o >>= 1) S += __shfl_xor(S, o, 64);
    float pn = e / S;
    if (lane < L) Pw[(size_t)g * L + lane] = pn;
    float sb = (lane < L) ? pn * v : 0.0f;
#pragma unroll
    for (int o = 32; o; o >>= 1) sb += __shfl_xor(sb, o, 64);
    if (lane == 0) isp[cb + offL + pos] = sb;
  }
  for (int n = 0; n < L; ++n) {
    int lc = offf(n) + pos;
    int rc = offf(L - 1 - n) + pos + n + 1;
    const float* A0r = PC + (cb + lc) * 1920;
    const float* A1r = PC + (cb + rc) * 1920 + 384;
    float* hrow = H + ((size_t)g * L + n) * DD;
    for (int k = tid; k < DD; k += 256)
      hrow[k] = sigma_h_f(A0r[k] + A1r[k] + B0[k]);
  }
}

// K1 outside: per (b,pos): sc[j] = dot(Uout[sib], oh[par]) + is_[sib] + os_[par],
// softmax p, sbar -> os_, H = sigma_h(P0[par] + S1[sib] + out_B0).
__global__ __launch_bounds__(256) void k1_out(
    const float* __restrict__ PC, const float* __restrict__ P0,
    const float* __restrict__ ohp, const float* __restrict__ isp,
    float* __restrict__ osp, float* __restrict__ H, float* __restrict__ Pw,
    const float* __restrict__ B0, int L, int Ls, int Nc, int offL) {
  int g = blockIdx.x;
  int b = g / Ls, pos = g - b * Ls;
  int tid = threadIdx.x, lane = tid & 63, wv = tid >> 6;
  __shared__ float scs[32];
  size_t cb = (size_t)b * NCELLS;
  int cnt0 = 31 - pos - L;
  for (int j = wv; j < Nc; j += 4) {
    int par, sib;
    if (j < cnt0) { par = offf(L + j + 1) + pos; sib = offf(j) + pos + L + 1; }
    else { int s2 = j - cnt0; par = offf(L + s2 + 1) + pos - s2 - 1; sib = offf(s2) + pos - s2 - 1; }
    const float* u = PC + (cb + sib) * 1920 + 1536;  // Uout[sib]
    const float* v = ohp + (cb + par) * (size_t)DD;  // oh[par]
    float s = 0.0f;
#pragma unroll
    for (int jj = 0; jj < 6; ++jj) s += u[lane + 64 * jj] * v[lane + 64 * jj];
#pragma unroll
    for (int o = 32; o; o >>= 1) s += __shfl_xor(s, o, 64);
    if (lane == 0) scs[j] = s + isp[cb + sib] + osp[cb + par];
  }
  __syncthreads();
  if (wv == 0) {
    float v = (lane < Nc) ? scs[lane] : -3.0e38f;
    float m = v;
#pragma unroll
    for (int o = 32; o; o >>= 1) m = fmaxf(m, __shfl_xor(m, o, 64));
    float e = (lane < Nc) ? __expf(v - m) : 0.0f;
    float S = e;
#pragma unroll
    for (int o = 32; o; o >>= 1) S += __shfl_xor(S, o, 64);
    float pn = e / S;
    if (lane < Nc) Pw[(size_t)g * Nc + lane] = pn;
    float sb = (lane < Nc) ? pn * v : 0.0f;
#pragma unroll
    for (int o = 32; o; o >>= 1) sb += __shfl_xor(sb, o, 64);
    if (lane == 0) osp[cb + offL + pos] = sb;
  }
  for (int j = 0; j < Nc; ++j) {
    int par, sib;
    if (j < cnt0) { par = offf(L + j + 1) + pos; sib = offf(j) + pos + L + 1; }
    else { int s2 = j - cnt0; par = offf(L + s2 + 1) + pos - s2 - 1; sib = offf(s2) + pos - s2 - 1; }
    const float* p0r = P0 + (cb + par) * (size_t)DD;
    const float* s1r = PC + (cb + sib) * 1920 + 1152;
    float* hrow = H + ((size_t)g * Nc + j) * DD;
    for (int k = tid; k < DD; k += 256)
      hrow[k] = sigma_h_f(p0r[k] + s1r[k] + B0[k]);
  }
}

// ---------------------------------------------------------------------------
// K3: hbar = LN(sum_n p[n]*XC[row n]) -> outArr cell. Pw==null => weight 1.
__global__ __launch_bounds__(128) void k3_red_ln(
    const float* __restrict__ XC, const float* __restrict__ Pw,
    const float* __restrict__ lng, const float* __restrict__ lnb,
    float* __restrict__ outArr, int L, int Ls, int offL) {
  int g = blockIdx.x;
  int b = g / Ls, pos = g - b * Ls;
  int tid = threadIdx.x;
  float a0 = 0, a1 = 0, a2 = 0;
  const float* base = XC + (size_t)g * L * DD;
  for (int n = 0; n < L; ++n) {
    float pw = Pw ? Pw[(size_t)g * L + n] : 1.0f;
    const float* row = base + (size_t)n * DD;
    a0 += pw * row[tid];
    a1 += pw * row[tid + 128];
    a2 += pw * row[tid + 256];
  }
  int lane = tid & 63, wv = tid >> 6;
  float s = a0 + a1 + a2;
#pragma unroll
  for (int o = 32; o; o >>= 1) s += __shfl_xor(s, o, 64);
  __shared__ float r1[2], r2[2];
  if (lane == 0) r1[wv] = s;
  __syncthreads();
  float mean = (r1[0] + r1[1]) * (1.0f / 384.0f);
  float d0 = a0 - mean, d1 = a1 - mean, d2 = a2 - mean;
  float q = d0 * d0 + d1 * d1 + d2 * d2;
#pragma unroll
  for (int o = 32; o; o >>= 1) q += __shfl_xor(q, o, 64);
  if (lane == 0) r2[wv] = q;
  __syncthreads();
  float var = (r2[0] + r2[1]) * (1.0f / 384.0f);
  float inv = rsqrtf(var + 1e-5f);
  float* out = outArr + ((size_t)b * NCELLS + offL + pos) * DD;
  out[tid]       = d0 * inv * lng[tid]       + lnb[tid];
  out[tid + 128] = d1 * inv * lng[tid + 128] + lnb[tid + 128];
  out[tid + 256] = d2 * inv * lng[tid + 256] + lnb[tid + 256];
}

// ---------------------------------------------------------------------------
// Root: oh[b][527] = LN(root_h), P0[b][527] = LN(root_h) @ out_W0.
__global__ __launch_bounds__(384) void root_k(
    const float* __restrict__ rooth, const float* __restrict__ lng,
    const float* __restrict__ lnb, const float* __restrict__ W0,
    float* __restrict__ ohp, float* __restrict__ P0) {
  int tid = threadIdx.x;          // 0..383
  int lane = tid & 63, wv = tid >> 6;
  __shared__ float rl[384];
  __shared__ float r1[6], r2[6];
  float x = rooth[tid];
  float s = x;
#pragma unroll
  for (int o = 32; o; o >>= 1) s += __shfl_xor(s, o, 64);
  if (lane == 0) r1[wv] = s;
  __syncthreads();
  float mean = (r1[0] + r1[1] + r1[2] + r1[3] + r1[4] + r1[5]) * (1.0f / 384.0f);
  float d = x - mean;
  float q = d * d;
#pragma unroll
  for (int o = 32; o; o >>= 1) q += __shfl_xor(q, o, 64);
  if (lane == 0) r2[wv] = q;
  __syncthreads();
  float var = (r2[0] + r2[1] + r2[2] + r2[3] + r2[4] + r2[5]) * (1.0f / 384.0f);
  float inv = rsqrtf(var + 1e-5f);
  float v = d * inv * lng[tid] + lnb[tid];
  rl[tid] = v;
  __syncthreads();
  for (int b2 = 0; b2 < BDIM; ++b2)
    ohp[((size_t)b2 * NCELLS + 527) * DD + tid] = v;
  float acc = 0.0f;
  for (int d2 = 0; d2 < 384; ++d2) acc += rl[d2] * W0[(size_t)d2 * 384 + tid];
  for (int b2 = 0; b2 < BDIM; ++b2)
    P0[((size_t)b2 * NCELLS + 527) * DD + tid] = acc;
}

// ---------------------------------------------------------------------------
extern "C" void kernel_launch(void* const* d_in, const int* in_sizes, int n_in,
                              void* d_out, int out_size, void* d_ws, size_t ws_size,
                              hipStream_t stream) {
  const float* x        = (const float*)d_in[0];
  const float* leaf_W   = (const float*)d_in[1];
  const float* leaf_b   = (const float*)d_in[2];
  const float* in_ln_g  = (const float*)d_in[3];
  const float* in_ln_b  = (const float*)d_in[4];
  const float* out_ln_g = (const float*)d_in[5];
  const float* out_ln_b = (const float*)d_in[6];
  const float* root_h   = (const float*)d_in[7];
  const float* in_bi    = (const float*)d_in[8];
  const float* out_bi   = (const float*)d_in[9];
  const float* in_W0    = (const float*)d_in[10];
  const float* in_W1    = (const float*)d_in[11];
  const float* in_B0    = (const float*)d_in[12];
  const float* in_W2    = (const float*)d_in[13];
  const float* in_B1    = (const float*)d_in[14];
  const float* out_W0   = (const float*)d_in[15];
  const float* out_W1   = (const float*)d_in[16];
  const float* out_B0   = (const float*)d_in[17];
  const float* out_W2   = (const float*)d_in[18];
  const float* out_B1   = (const float*)d_in[19];

  float* ih  = (float*)d_out;
  float* isp = ih + (size_t)BDIM * NCELLS * DD;
  float* oh  = isp + (size_t)BDIM * NCELLS;
  float* osp = oh + (size_t)BDIM * NCELLS * DD;

  float* PC   = (float*)d_ws;                               // B*NCELLS*1920
  float* P0   = PC + (size_t)BDIM * NCELLS * 1920;          // B*NCELLS*384
  float* WC   = P0 + (size_t)BDIM * NCELLS * 384;           // 384*1920
  float* Hbuf = WC + (size_t)384 * 1920;                    // 31744*384
  float* XCb  = Hbuf + (size_t)31744 * 384;                 // 31744*384
  float* Pw   = XCb + (size_t)31744 * 384;                  // 31744

  // pack weights + zero score arrays
  pack_k<<<576, 256, 0, stream>>>(in_W0, in_W1, in_bi, out_W1, out_bi, WC, isp, osp);

  // leaf: T = sigma_h(x @ leaf_W + leaf_b); ih[level0] = LN(T); PC for leaves
  gemm_k<<<dim3(16, 3), 256, 0, stream>>>(x, leaf_W, leaf_b, Hbuf, 1024, 384, 1, 0, 0);
  k3_red_ln<<<1024, 128, 0, stream>>>(Hbuf, nullptr, in_ln_g, in_ln_b, ih, 1, 32, 0);
  gemm_k<<<dim3(16, 15), 256, 0, stream>>>(ih, WC, nullptr, PC, 1024, 1920, 0, 32, 0);

  // inside pass
  for (int L = 1; L < LEN; ++L) {
    int Ls = LEN - L, G = BDIM * Ls, M = G * L, off = offh(L);
    k1_in<<<G, 256, 0, stream>>>(PC, ih, isp, Hbuf, Pw, in_B0, L, Ls, off);
    gemm_k<<<dim3((M + BM - 1) / BM, 3), 256, 0, stream>>>(Hbuf, in_W2, in_B1, XCb, M, 384, 1, 0, 0);
    k3_red_ln<<<G, 128, 0, stream>>>(XCb, Pw, in_ln_g, in_ln_b, ih, L, Ls, off);
    gemm_k<<<dim3((G + BM - 1) / BM, 15), 256, 0, stream>>>(ih, WC, nullptr, PC, G, 1920, 0, Ls, off);
  }

  // root
  root_k<<<1, 384, 0, stream>>>(root_h, out_ln_g, out_ln_b, out_W0, oh, P0);

  // outside pass
  for (int L = LEN - 2; L >= 0; --L) {
    int Ls = LEN - L, Nc = LEN - 1 - L, G = BDIM * Ls, M = G * Nc, off = offh(L);
    k1_out<<<G, 256, 0, stream>>>(PC, P0, oh, isp, osp, Hbuf, Pw, out_B0, L, Ls, Nc, off);
    gemm_k<<<dim3((M + BM - 1) / BM, 3), 256, 0, stream>>>(Hbuf, out_W2, out_B1, XCb, M, 384, 1, 0, 0);
    k3_red_ln<<<G, 128, 0, stream>>>(XCb, Pw, out_ln_g, out_ln_b, oh, Nc, Ls, off);
    if (L > 0)
      gemm_k<<<dim3((G + BM - 1) / BM, 3), 256, 0, stream>>>(oh, out_W0, nullptr, P0, G, 384, 0, Ls, off);
  }
}

// Round 3
// 5126.160 us; speedup vs baseline: 1.7233x; 1.7233x over previous
//
#include <hip/hip_runtime.h>
#include <cstddef>

#define BDIM 32
#define LEN 32
#define DD 384
#define NCELLS 528

typedef _Float16 h16;
typedef __attribute__((ext_vector_type(8))) _Float16 v8h;
typedef __attribute__((ext_vector_type(4))) float v4f;

__device__ __forceinline__ int offf(int k) { return k * 32 - ((k * (k - 1)) >> 1); }
static inline int offh(int k) { return k * 32 - ((k * (k - 1)) >> 1); }

__device__ __forceinline__ float sigma_h_f(float x) {
  float s = 1.0f / (1.0f + __expf(-x));      // sigmoid
  float r = sqrtf(s);
  float e2 = __expf(2.0f * r);
  float th = 1.0f - 2.0f / (e2 + 1.0f);      // tanh(r), r in (0,1)
  return x * th;
}

__device__ __forceinline__ size_t rowbase(int r, int gLs, int gOff) {
  if (gLs == 0) return (size_t)r;
  int b = r / gLs;
  int p = r - b * gLs;
  return (size_t)b * NCELLS + gOff + p;
}

// ---------------------------------------------------------------------------
// pack3: fp32 transposed weights + zero score arrays.
// WCt[1920][384] = [in_W0|in_W1|in_bi|out_W1|out_bi]^T ; W*t[n][k] = W[k][n].
__global__ __launch_bounds__(256) void pack3_k(
    const float* __restrict__ w0, const float* __restrict__ w1,
    const float* __restrict__ bi, const float* __restrict__ ow1,
    const float* __restrict__ obi, const float* __restrict__ w2,
    const float* __restrict__ ow2, const float* __restrict__ ow0,
    const float* __restrict__ lw,
    float* __restrict__ WCt, float* __restrict__ W2t, float* __restrict__ OW2t,
    float* __restrict__ OW0t, float* __restrict__ LWt,
    float* __restrict__ isp, float* __restrict__ osp) {
  int i = blockIdx.x * 256 + threadIdx.x;
  if (i < 1920 * 384) {
    int n = i / 384, k = i - n * 384;
    int sel = n / 384, c = n - sel * 384;
    const float* src = sel == 0 ? w0 : sel == 1 ? w1 : sel == 2 ? bi
                       : sel == 3 ? ow1 : obi;
    WCt[i] = src[k * 384 + c];
  }
  if (i < 384 * 384) {
    int n = i / 384, k = i - n * 384;
    W2t[i]  = w2[k * 384 + n];
    OW2t[i] = ow2[k * 384 + n];
    OW0t[i] = ow0[k * 384 + n];
    LWt[i]  = lw[k * 384 + n];
  }
  if (i < BDIM * NCELLS) { isp[i] = 0.0f; osp[i] = 0.0f; }
}

// ---------------------------------------------------------------------------
// Split-f16 MFMA GEMM with ~fp32 accuracy:
// C[M][N](f32) = act(A[M][384](f32) @ Wt^T + bias),  Wt[N][384] f32.
// Operands split on staging: a = hi + lo (both f16); 3 MFMAs per tile pair.
// Block tile 64x128, 4 waves each 64x32. Row gather via rowbase.
__global__ __launch_bounds__(256) void gemm32s(
    const float* __restrict__ A, const float* __restrict__ Wt,
    const float* __restrict__ bias, float* __restrict__ C,
    int M, int N, int act, int gLs, int gOff) {
  __shared__ h16 Ah[64][40], Al[64][40];
  __shared__ h16 Bh[128][40], Bl[128][40];
  int tid = threadIdx.x;
  int w = tid >> 6, lane = tid & 63;
  int m0 = blockIdx.x * 64, n0 = blockIdx.y * 128;
  int r = lane & 15, q = lane >> 4;

  v4f acc[4][2];
#pragma unroll
  for (int i = 0; i < 4; ++i)
#pragma unroll
    for (int j = 0; j < 2; ++j) acc[i][j] = (v4f){0.f, 0.f, 0.f, 0.f};

  int sar = tid >> 2;           // A row 0..63
  int sak = (tid & 3) << 3;     // A k-chunk: 8 floats
  const float* Aptr = nullptr;
  if (m0 + sar < M) Aptr = A + rowbase(m0 + sar, gLs, gOff) * (size_t)DD;
  int sbc = tid >> 1;           // B col 0..127
  int sbk = (tid & 1) << 4;     // B k-chunk: 16 floats
  const float* Bptr = Wt + (size_t)(n0 + sbc) * DD;

  for (int k0 = 0; k0 < DD; k0 += 32) {
    float4 a0 = make_float4(0.f, 0.f, 0.f, 0.f), a1 = a0;
    if (Aptr) {
      a0 = *reinterpret_cast<const float4*>(Aptr + k0 + sak);
      a1 = *reinterpret_cast<const float4*>(Aptr + k0 + sak + 4);
    }
    float4 b0 = *reinterpret_cast<const float4*>(Bptr + k0 + sbk);
    float4 b1 = *reinterpret_cast<const float4*>(Bptr + k0 + sbk + 4);
    float4 b2 = *reinterpret_cast<const float4*>(Bptr + k0 + sbk + 8);
    float4 b3 = *reinterpret_cast<const float4*>(Bptr + k0 + sbk + 12);
    __syncthreads();
    {
      float av[8] = {a0.x, a0.y, a0.z, a0.w, a1.x, a1.y, a1.z, a1.w};
      v8h hi, lo;
#pragma unroll
      for (int t = 0; t < 8; ++t) {
        h16 h = (h16)av[t];
        hi[t] = h;
        lo[t] = (h16)(av[t] - (float)h);
      }
      *reinterpret_cast<v8h*>(&Ah[sar][sak]) = hi;
      *reinterpret_cast<v8h*>(&Al[sar][sak]) = lo;
    }
    {
      float bv[16] = {b0.x, b0.y, b0.z, b0.w, b1.x, b1.y, b1.z, b1.w,
                      b2.x, b2.y, b2.z, b2.w, b3.x, b3.y, b3.z, b3.w};
      v8h hi0, lo0, hi1, lo1;
#pragma unroll
      for (int t = 0; t < 8; ++t) {
        h16 h = (h16)bv[t];
        hi0[t] = h;
        lo0[t] = (h16)(bv[t] - (float)h);
      }
#pragma unroll
      for (int t = 0; t < 8; ++t) {
        h16 h = (h16)bv[8 + t];
        hi1[t] = h;
        lo1[t] = (h16)(bv[8 + t] - (float)h);
      }
      *reinterpret_cast<v8h*>(&Bh[sbc][sbk]) = hi0;
      *reinterpret_cast<v8h*>(&Bl[sbc][sbk]) = lo0;
      *reinterpret_cast<v8h*>(&Bh[sbc][sbk + 8]) = hi1;
      *reinterpret_cast<v8h*>(&Bl[sbc][sbk + 8]) = lo1;
    }
    __syncthreads();
    v8h afh[4], afl[4], bfh[2], bfl[2];
#pragma unroll
    for (int i = 0; i < 4; ++i) {
      afh[i] = *reinterpret_cast<const v8h*>(&Ah[i * 16 + r][q * 8]);
      afl[i] = *reinterpret_cast<const v8h*>(&Al[i * 16 + r][q * 8]);
    }
#pragma unroll
    for (int j = 0; j < 2; ++j) {
      bfh[j] = *reinterpret_cast<const v8h*>(&Bh[w * 32 + j * 16 + r][q * 8]);
      bfl[j] = *reinterpret_cast<const v8h*>(&Bl[w * 32 + j * 16 + r][q * 8]);
    }
#pragma unroll
    for (int i = 0; i < 4; ++i)
#pragma unroll
      for (int j = 0; j < 2; ++j) {
        acc[i][j] = __builtin_amdgcn_mfma_f32_16x16x32_f16(afl[i], bfh[j], acc[i][j], 0, 0, 0);
        acc[i][j] = __builtin_amdgcn_mfma_f32_16x16x32_f16(afh[i], bfl[j], acc[i][j], 0, 0, 0);
        acc[i][j] = __builtin_amdgcn_mfma_f32_16x16x32_f16(afh[i], bfh[j], acc[i][j], 0, 0, 0);
      }
  }

#pragma unroll
  for (int i = 0; i < 4; ++i) {
#pragma unroll
    for (int reg = 0; reg < 4; ++reg) {
      int rr = m0 + i * 16 + q * 4 + reg;
      if (rr >= M) continue;
      size_t cb = rowbase(rr, gLs, gOff) * (size_t)N;
#pragma unroll
      for (int j = 0; j < 2; ++j) {
        int col = n0 + w * 32 + j * 16 + r;
        float v = acc[i][j][reg];
        if (bias) v += bias[col];
        if (act) v = sigma_h_f(v);
        C[cb + col] = v;
      }
    }
  }
}

// ---------------------------------------------------------------------------
// K1 inside: scores+softmax+sbar -> is_, and H rows (f32).
__global__ __launch_bounds__(256) void k1_in(
    const float* __restrict__ PC, const float* __restrict__ ihp,
    float* __restrict__ isp, float* __restrict__ H, float* __restrict__ Pw,
    const float* __restrict__ B0, int L, int Ls, int offL) {
  int g = blockIdx.x;
  int b = g / Ls, pos = g - b * Ls;
  int tid = threadIdx.x, lane = tid & 63, wv = tid >> 6;
  __shared__ float scs[32];
  size_t cb = (size_t)b * NCELLS;
  for (int n = wv; n < L; n += 4) {
    int lc = offf(n) + pos;
    int rc = offf(L - 1 - n) + pos + n + 1;
    const float* u = PC + (cb + lc) * 1920 + 768;   // Uin[l]
    const float* v = ihp + (cb + rc) * (size_t)DD;  // ih[r]
    float s = 0.0f;
#pragma unroll
    for (int jj = 0; jj < 6; ++jj) s += u[lane + 64 * jj] * v[lane + 64 * jj];
#pragma unroll
    for (int o = 32; o; o >>= 1) s += __shfl_xor(s, o, 64);
    if (lane == 0) scs[n] = s + isp[cb + lc] + isp[cb + rc];
  }
  __syncthreads();
  if (wv == 0) {
    float v = (lane < L) ? scs[lane] : -3.0e38f;
    float m = v;
#pragma unroll
    for (int o = 32; o; o >>= 1) m = fmaxf(m, __shfl_xor(m, o, 64));
    float e = (lane < L) ? __expf(v - m) : 0.0f;
    float S = e;
#pragma unroll
    for (int o = 32; o; o >>= 1) S += __shfl_xor(S, o, 64);
    float pn = e / S;
    if (lane < L) Pw[(size_t)g * L + lane] = pn;
    float sb = (lane < L) ? pn * v : 0.0f;
#pragma unroll
    for (int o = 32; o; o >>= 1) sb += __shfl_xor(sb, o, 64);
    if (lane == 0) isp[cb + offL + pos] = sb;
  }
  for (int n = 0; n < L; ++n) {
    int lc = offf(n) + pos;
    int rc = offf(L - 1 - n) + pos + n + 1;
    const float* A0r = PC + (cb + lc) * 1920;
    const float* A1r = PC + (cb + rc) * 1920 + 384;
    float* hrow = H + ((size_t)g * L + n) * DD;
    for (int k = tid; k < DD; k += 256)
      hrow[k] = sigma_h_f(A0r[k] + A1r[k] + B0[k]);
  }
}

// K1 outside.
__global__ __launch_bounds__(256) void k1_out(
    const float* __restrict__ PC, const float* __restrict__ P0,
    const float* __restrict__ ohp, const float* __restrict__ isp,
    float* __restrict__ osp, float* __restrict__ H, float* __restrict__ Pw,
    const float* __restrict__ B0, int L, int Ls, int Nc, int offL) {
  int g = blockIdx.x;
  int b = g / Ls, pos = g - b * Ls;
  int tid = threadIdx.x, lane = tid & 63, wv = tid >> 6;
  __shared__ float scs[32];
  size_t cb = (size_t)b * NCELLS;
  int cnt0 = 31 - pos - L;
  for (int j = wv; j < Nc; j += 4) {
    int par, sib;
    if (j < cnt0) { par = offf(L + j + 1) + pos; sib = offf(j) + pos + L + 1; }
    else { int s2 = j - cnt0; par = offf(L + s2 + 1) + pos - s2 - 1; sib = offf(s2) + pos - s2 - 1; }
    const float* u = PC + (cb + sib) * 1920 + 1536;  // Uout[sib]
    const float* v = ohp + (cb + par) * (size_t)DD;  // oh[par]
    float s = 0.0f;
#pragma unroll
    for (int jj = 0; jj < 6; ++jj) s += u[lane + 64 * jj] * v[lane + 64 * jj];
#pragma unroll
    for (int o = 32; o; o >>= 1) s += __shfl_xor(s, o, 64);
    if (lane == 0) scs[j] = s + isp[cb + sib] + osp[cb + par];
  }
  __syncthreads();
  if (wv == 0) {
    float v = (lane < Nc) ? scs[lane] : -3.0e38f;
    float m = v;
#pragma unroll
    for (int o = 32; o; o >>= 1) m = fmaxf(m, __shfl_xor(m, o, 64));
    float e = (lane < Nc) ? __expf(v - m) : 0.0f;
    float S = e;
#pragma unroll
    for (int o = 32; o; o >>= 1) S += __shfl_xor(S, o, 64);
    float pn = e / S;
    if (lane < Nc) Pw[(size_t)g * Nc + lane] = pn;
    float sb = (lane < Nc) ? pn * v : 0.0f;
#pragma unroll
    for (int o = 32; o; o >>= 1) sb += __shfl_xor(sb, o, 64);
    if (lane == 0) osp[cb + offL + pos] = sb;
  }
  for (int j = 0; j < Nc; ++j) {
    int par, sib;
    if (j < cnt0) { par = offf(L + j + 1) + pos; sib = offf(j) + pos + L + 1; }
    else { int s2 = j - cnt0; par = offf(L + s2 + 1) + pos - s2 - 1; sib = offf(s2) + pos - s2 - 1; }
    const float* p0r = P0 + (cb + par) * (size_t)DD;
    const float* s1r = PC + (cb + sib) * 1920 + 1152;
    float* hrow = H + ((size_t)g * Nc + j) * DD;
    for (int k = tid; k < DD; k += 256)
      hrow[k] = sigma_h_f(p0r[k] + s1r[k] + B0[k]);
  }
}

// ---------------------------------------------------------------------------
// K3: hbar = LN(sum_n p[n]*XC[row n]) -> outArr cell. Pw==null => weight 1.
__global__ __launch_bounds__(128) void k3_red_ln(
    const float* __restrict__ XC, const float* __restrict__ Pw,
    const float* __restrict__ lng, const float* __restrict__ lnb,
    float* __restrict__ outArr, int L, int Ls, int offL) {
  int g = blockIdx.x;
  int b = g / Ls, pos = g - b * Ls;
  int tid = threadIdx.x;
  float a0 = 0, a1 = 0, a2 = 0;
  const float* base = XC + (size_t)g * L * DD;
  for (int n = 0; n < L; ++n) {
    float pw = Pw ? Pw[(size_t)g * L + n] : 1.0f;
    const float* row = base + (size_t)n * DD;
    a0 += pw * row[tid];
    a1 += pw * row[tid + 128];
    a2 += pw * row[tid + 256];
  }
  int lane = tid & 63, wv = tid >> 6;
  float s = a0 + a1 + a2;
#pragma unroll
  for (int o = 32; o; o >>= 1) s += __shfl_xor(s, o, 64);
  __shared__ float r1[2], r2[2];
  if (lane == 0) r1[wv] = s;
  __syncthreads();
  float mean = (r1[0] + r1[1]) * (1.0f / 384.0f);
  float d0 = a0 - mean, d1 = a1 - mean, d2 = a2 - mean;
  float q = d0 * d0 + d1 * d1 + d2 * d2;
#pragma unroll
  for (int o = 32; o; o >>= 1) q += __shfl_xor(q, o, 64);
  if (lane == 0) r2[wv] = q;
  __syncthreads();
  float var = (r2[0] + r2[1]) * (1.0f / 384.0f);
  float inv = rsqrtf(var + 1e-5f);
  float* out = outArr + ((size_t)b * NCELLS + offL + pos) * DD;
  out[tid]       = d0 * inv * lng[tid]       + lnb[tid];
  out[tid + 128] = d1 * inv * lng[tid + 128] + lnb[tid + 128];
  out[tid + 256] = d2 * inv * lng[tid + 256] + lnb[tid + 256];
}

// ---------------------------------------------------------------------------
// Root: oh[b][527] = LN(root_h), P0[b][527] = LN(root_h) @ out_W0.
__global__ __launch_bounds__(384) void root_k(
    const float* __restrict__ rooth, const float* __restrict__ lng,
    const float* __restrict__ lnb, const float* __restrict__ W0,
    float* __restrict__ ohp, float* __restrict__ P0) {
  int tid = threadIdx.x;
  int lane = tid & 63, wv = tid >> 6;
  __shared__ float rl[384];
  __shared__ float r1[6], r2[6];
  float x = rooth[tid];
  float s = x;
#pragma unroll
  for (int o = 32; o; o >>= 1) s += __shfl_xor(s, o, 64);
  if (lane == 0) r1[wv] = s;
  __syncthreads();
  float mean = (r1[0] + r1[1] + r1[2] + r1[3] + r1[4] + r1[5]) * (1.0f / 384.0f);
  float d = x - mean;
  float q = d * d;
#pragma unroll
  for (int o = 32; o; o >>= 1) q += __shfl_xor(q, o, 64);
  if (lane == 0) r2[wv] = q;
  __syncthreads();
  float var = (r2[0] + r2[1] + r2[2] + r2[3] + r2[4] + r2[5]) * (1.0f / 384.0f);
  float inv = rsqrtf(var + 1e-5f);
  float v = d * inv * lng[tid] + lnb[tid];
  rl[tid] = v;
  __syncthreads();
  for (int b2 = 0; b2 < BDIM; ++b2)
    ohp[((size_t)b2 * NCELLS + 527) * DD + tid] = v;
  float acc = 0.0f;
  for (int d2 = 0; d2 < 384; ++d2) acc += rl[d2] * W0[(size_t)d2 * 384 + tid];
  for (int b2 = 0; b2 < BDIM; ++b2)
    P0[((size_t)b2 * NCELLS + 527) * DD + tid] = acc;
}

// ---------------------------------------------------------------------------
extern "C" void kernel_launch(void* const* d_in, const int* in_sizes, int n_in,
                              void* d_out, int out_size, void* d_ws, size_t ws_size,
                              hipStream_t stream) {
  const float* x        = (const float*)d_in[0];
  const float* leaf_W   = (const float*)d_in[1];
  const float* leaf_b   = (const float*)d_in[2];
  const float* in_ln_g  = (const float*)d_in[3];
  const float* in_ln_b  = (const float*)d_in[4];
  const float* out_ln_g = (const float*)d_in[5];
  const float* out_ln_b = (const float*)d_in[6];
  const float* root_h   = (const float*)d_in[7];
  const float* in_bi    = (const float*)d_in[8];
  const float* out_bi   = (const float*)d_in[9];
  const float* in_W0    = (const float*)d_in[10];
  const float* in_W1    = (const float*)d_in[11];
  const float* in_B0    = (const float*)d_in[12];
  const float* in_W2    = (const float*)d_in[13];
  const float* in_B1    = (const float*)d_in[14];
  const float* out_W0   = (const float*)d_in[15];
  const float* out_W1   = (const float*)d_in[16];
  const float* out_B0   = (const float*)d_in[17];
  const float* out_W2   = (const float*)d_in[18];
  const float* out_B1   = (const float*)d_in[19];

  float* ih  = (float*)d_out;
  float* isp = ih + (size_t)BDIM * NCELLS * DD;
  float* oh  = isp + (size_t)BDIM * NCELLS;
  float* osp = oh + (size_t)BDIM * NCELLS * DD;

  float* PC   = (float*)d_ws;                               // B*NCELLS*1920
  float* P0   = PC + (size_t)BDIM * NCELLS * 1920;          // B*NCELLS*384
  float* XCb  = P0 + (size_t)BDIM * NCELLS * 384;           // 31744*384
  float* Hbuf = XCb + (size_t)31744 * 384;                  // 31744*384
  float* Pw   = Hbuf + (size_t)31744 * 384;                 // 31744
  float* WCt  = Pw + 31744;                                 // 1920*384
  float* W2t  = WCt + (size_t)1920 * 384;                   // 384*384
  float* OW2t = W2t + (size_t)384 * 384;
  float* OW0t = OW2t + (size_t)384 * 384;
  float* LWt  = OW0t + (size_t)384 * 384;

  pack3_k<<<2880, 256, 0, stream>>>(in_W0, in_W1, in_bi, out_W1, out_bi,
                                    in_W2, out_W2, out_W0, leaf_W,
                                    WCt, W2t, OW2t, OW0t, LWt, isp, osp);

  // leaf: T = sigma_h(x @ leaf_W + b); ih[level0] = LN(T); PC for leaves
  gemm32s<<<dim3(16, 3), 256, 0, stream>>>(x, LWt, leaf_b, XCb, 1024, 384, 1, 0, 0);
  k3_red_ln<<<1024, 128, 0, stream>>>(XCb, nullptr, in_ln_g, in_ln_b, ih, 1, 32, 0);
  gemm32s<<<dim3(16, 15), 256, 0, stream>>>(ih, WCt, nullptr, PC, 1024, 1920, 0, 32, 0);

  // inside pass
  for (int L = 1; L < LEN; ++L) {
    int Ls = LEN - L, G = BDIM * Ls, M = G * L, off = offh(L);
    k1_in<<<G, 256, 0, stream>>>(PC, ih, isp, Hbuf, Pw, in_B0, L, Ls, off);
    gemm32s<<<dim3((M + 63) / 64, 3), 256, 0, stream>>>(Hbuf, W2t, in_B1, XCb, M, 384, 1, 0, 0);
    k3_red_ln<<<G, 128, 0, stream>>>(XCb, Pw, in_ln_g, in_ln_b, ih, L, Ls, off);
    gemm32s<<<dim3((G + 63) / 64, 15), 256, 0, stream>>>(ih, WCt, nullptr, PC, G, 1920, 0, Ls, off);
  }

  // root
  root_k<<<1, 384, 0, stream>>>(root_h, out_ln_g, out_ln_b, out_W0, oh, P0);

  // outside pass
  for (int L = LEN - 2; L >= 0; --L) {
    int Ls = LEN - L, Nc = LEN - 1 - L, G = BDIM * Ls, M = G * Nc, off = offh(L);
    k1_out<<<G, 256, 0, stream>>>(PC, P0, oh, isp, osp, Hbuf, Pw, out_B0, L, Ls, Nc, off);
    gemm32s<<<dim3((M + 63) / 64, 3), 256, 0, stream>>>(Hbuf, OW2t, out_B1, XCb, M, 384, 1, 0, 0);
    k3_red_ln<<<G, 128, 0, stream>>>(XCb, Pw, out_ln_g, out_ln_b, oh, Nc, Ls, off);
    if (L > 0)
      gemm32s<<<dim3((G + 63) / 64, 3), 256, 0, stream>>>(oh, OW0t, nullptr, P0, G, 384, 0, Ls, off);
  }
}